// Round 5
// baseline (142.299 us; speedup 1.0000x reference)
//
#include <hip/hip_runtime.h>

// x: [B=16, T=16384, C=64] fp32. bp_sos/lp_sos: [2,6] fp32 rows (b0,b1,b2,a0,a1,a2; a0==1).
#define B_LEN 16
#define T_LEN 16384
#define C_LEN 64
#define CHUNK 32    // output samples per thread (32 -> 2048 blocks = 8 blocks/CU = full 32 waves/CU)
#define WARM  64    // zero-state warmup; transient ~0.83^64 ~ 7e-6 (empirically safe: absmax 0.0156 at R2)

// One thread per (channel, chunk). Lanes cover the 64 channels of one batch entry ->
// every load/store is one contiguous 256B wave transaction. Each thread runs the
// 4-biquad cascade (bp0, bp1, square, lp0, lp1) over warm+CHUNK samples, discarding
// the first `warm` outputs. warm = min(WARM, chunk*CHUNK): clamped to available
// history (R3/R4 crashed on t0<0 OOB reads when CHUNK<WARM without this clamp);
// chunks 0..WARM/CHUNK are exact (they start at t=0 with the true zero state).
// Memory roofline: 64MB in + 64MB out = ~21 us at 6.3 TB/s.
__global__ __launch_bounds__(256) void iir_chunked_kernel(
    const float* __restrict__ x,
    const float* __restrict__ bp,
    const float* __restrict__ lp,
    float* __restrict__ out)
{
    const int c     = threadIdx.x & 63;        // channel within batch
    const int bsub  = threadIdx.x >> 6;        // 0..3
    const int b     = blockIdx.y * 4 + bsub;   // batch 0..15
    const int chunk = blockIdx.x;              // 0..T/CHUNK-1

    // Uniform coefficients -> scalar loads, hoisted. Negate a's so the chain is pure FMA.
    const float b10 = bp[0], b11 = bp[1], b12 = bp[2],  a11 = -bp[4],  a12 = -bp[5];
    const float b20 = bp[6], b21 = bp[7], b22 = bp[8],  a21 = -bp[10], a22 = -bp[11];
    const float b30 = lp[0], b31 = lp[1], b32 = lp[2],  a31 = -lp[4],  a32 = -lp[5];
    const float b40 = lp[6], b41 = lp[7], b42 = lp[8],  a41 = -lp[10], a42 = -lp[11];

    const int t_out0 = chunk * CHUNK;
    const int warm   = (t_out0 < WARM) ? t_out0 : WARM;  // block-uniform, t0 >= 0 always
    const int t0     = t_out0 - warm;

    // Direct-form-I state for 4 sections
    float s1x1 = 0.f, s1x2 = 0.f, s1y1 = 0.f, s1y2 = 0.f;
    float s2x1 = 0.f, s2x2 = 0.f, s2y1 = 0.f, s2y2 = 0.f;
    float s3x1 = 0.f, s3x2 = 0.f, s3y1 = 0.f, s3y2 = 0.f;
    float s4x1 = 0.f, s4x2 = 0.f, s4y1 = 0.f, s4y2 = 0.f;

    int idx = (b * T_LEN + t0) * C_LEN + c;

    auto step = [&](float xn) -> float {
        float y1 = b10 * xn + b11 * s1x1 + b12 * s1x2 + a11 * s1y1 + a12 * s1y2;
        s1x2 = s1x1; s1x1 = xn; s1y2 = s1y1; s1y1 = y1;
        float y2 = b20 * y1 + b21 * s2x1 + b22 * s2x2 + a21 * s2y1 + a22 * s2y2;
        s2x2 = s2x1; s2x1 = y1; s2y2 = s2y1; s2y1 = y2;
        float v = y2 * y2;
        float y3 = b30 * v + b31 * s3x1 + b32 * s3x2 + a31 * s3y1 + a32 * s3y2;
        s3x2 = s3x1; s3x1 = v; s3y2 = s3y1; s3y1 = y3;
        float y4 = b40 * y3 + b41 * s4x1 + b42 * s4x2 + a41 * s4y1 + a42 * s4y2;
        s4x2 = s4x1; s4x1 = y3; s4y2 = s4y1; s4y1 = y4;
        return y4;
    };

    // Warmup: run cascade, discard outputs. unroll 4 lets the compiler rename the
    // state shift-chain away (no v_mov per sample).
#pragma unroll 4
    for (int i = 0; i < warm; ++i) {
        float xn = x[idx];
        idx += C_LEN;
        step(xn);
    }
    // Emit CHUNK outputs.
#pragma unroll 4
    for (int i = 0; i < CHUNK; ++i) {
        float xn = x[idx];
        out[idx] = step(xn);
        idx += C_LEN;
    }
}

extern "C" void kernel_launch(void* const* d_in, const int* in_sizes, int n_in,
                              void* d_out, int out_size, void* d_ws, size_t ws_size,
                              hipStream_t stream) {
    const float* x  = (const float*)d_in[0];
    const float* bp = (const float*)d_in[1];
    const float* lp = (const float*)d_in[2];
    float* out      = (float*)d_out;

    dim3 grid(T_LEN / CHUNK, B_LEN / 4);   // 512 x 4 = 2048 blocks = 8 blocks/CU
    dim3 block(256);                        // 4 waves: 4 batches x 64 channels
    iir_chunked_kernel<<<grid, block, 0, stream>>>(x, bp, lp, out);
}

// Round 6
// 126.220 us; speedup vs baseline: 1.1274x; 1.1274x over previous
//
#include <hip/hip_runtime.h>

// x: [B=16, T=16384, C=64] fp32. bp_sos/lp_sos: [2,6] fp32 rows (b0,b1,b2,a0,a1,a2; a0==1).
#define B_LEN 16
#define T_LEN 16384
#define C_LEN 64
#define CHUNK 64    // output samples per thread; 2x compute amp (warm 64) — R5 showed 3x amp (CHUNK=32) loses
#define WARM  64    // zero-state warmup; transient ~0.83^64 ~ 7e-6 (empirically safe: absmax 0.0156)

// One thread per (channel, chunk); lanes cover the 64 channels of one batch entry ->
// every load/store is one contiguous 256B wave transaction.
// Biquads in TRANSPOSED DIRECT-FORM II: 5 FMA/section, no state shifts, crit path
// ~1 FMA/section (vs DF-I's ~4). R5 post-mortem measured ~45 VALU insts/sample for
// DF-I (shift movs + 4-deep accumulation chains); DF2T cuts to ~21.
// warm = min(WARM, chunk*CHUNK): clamped to available history (t0 >= 0 always;
// R3/R4 aborted on OOB reads when CHUNK<WARM without this). Early chunks are exact.
__global__ __launch_bounds__(256) void iir_chunked_kernel(
    const float* __restrict__ x,
    const float* __restrict__ bp,
    const float* __restrict__ lp,
    float* __restrict__ out)
{
    const int c     = threadIdx.x & 63;        // channel within batch
    const int bsub  = threadIdx.x >> 6;        // 0..3
    const int b     = blockIdx.y * 4 + bsub;   // batch 0..15
    const int chunk = blockIdx.x;              // 0..T/CHUNK-1

    // Uniform coefficients -> scalar (SGPR) loads. a's negated so updates are pure FMA.
    const float b10 = bp[0], b11 = bp[1], b12 = bp[2],  a11 = -bp[4],  a12 = -bp[5];
    const float b20 = bp[6], b21 = bp[7], b22 = bp[8],  a21 = -bp[10], a22 = -bp[11];
    const float b30 = lp[0], b31 = lp[1], b32 = lp[2],  a31 = -lp[4],  a32 = -lp[5];
    const float b40 = lp[6], b41 = lp[7], b42 = lp[8],  a41 = -lp[10], a42 = -lp[11];

    const int t_out0 = chunk * CHUNK;
    const int warm   = (t_out0 < WARM) ? t_out0 : WARM;  // block-uniform, t0 >= 0 always
    const int t0     = t_out0 - warm;

    // DF2T state: 2 per section
    float s11 = 0.f, s12 = 0.f;
    float s21 = 0.f, s22 = 0.f;
    float s31 = 0.f, s32 = 0.f;
    float s41 = 0.f, s42 = 0.f;

    int idx = (b * T_LEN + t0) * C_LEN + c;

    auto step = [&](float xn) -> float {
        // section 1 (bandpass)
        float y1 = fmaf(b10, xn, s11);
        s11 = fmaf(b11, xn, fmaf(a11, y1, s12));
        s12 = fmaf(b12, xn, a12 * y1);
        // section 2 (bandpass)
        float y2 = fmaf(b20, y1, s21);
        s21 = fmaf(b21, y1, fmaf(a21, y2, s22));
        s22 = fmaf(b22, y1, a22 * y2);
        // squaring nonlinearity
        float v = y2 * y2;
        // section 3 (lowpass)
        float y3 = fmaf(b30, v, s31);
        s31 = fmaf(b31, v, fmaf(a31, y3, s32));
        s32 = fmaf(b32, v, a32 * y3);
        // section 4 (lowpass)
        float y4 = fmaf(b40, y3, s41);
        s41 = fmaf(b41, y3, fmaf(a41, y4, s42));
        s42 = fmaf(b42, y3, a42 * y4);
        return y4;
    };

    // Warmup: run cascade, discard outputs. unroll 8 batches the loads so the
    // compiler issues them ahead of the dependent FMA chains.
#pragma unroll 8
    for (int i = 0; i < warm; ++i) {
        float xn = x[idx];
        idx += C_LEN;
        step(xn);
    }
    // Emit CHUNK outputs.
#pragma unroll 8
    for (int i = 0; i < CHUNK; ++i) {
        float xn = x[idx];
        out[idx] = step(xn);
        idx += C_LEN;
    }
}

extern "C" void kernel_launch(void* const* d_in, const int* in_sizes, int n_in,
                              void* d_out, int out_size, void* d_ws, size_t ws_size,
                              hipStream_t stream) {
    const float* x  = (const float*)d_in[0];
    const float* bp = (const float*)d_in[1];
    const float* lp = (const float*)d_in[2];
    float* out      = (float*)d_out;

    dim3 grid(T_LEN / CHUNK, B_LEN / 4);   // 256 x 4 = 1024 blocks
    dim3 block(256);                        // 4 waves: 4 batches x 64 channels
    iir_chunked_kernel<<<grid, block, 0, stream>>>(x, bp, lp, out);
}